// Round 2
// baseline (375.131 us; speedup 1.0000x reference)
//
#include <hip/hip_runtime.h>

#define SN_NA    800
#define SN_F     128
#define SN_G     50
#define SN_MAXN  128
#define SN_MAXP  16384
#define SN_BP    8
#define SN_CUT2  25.0f

// ---- workspace layout (bytes) ----
#define WO_FLAG  0
#define WO_PCNT  64
#define WO_NCNT  128
#define WO_NBRP  3584
#define WO_NBRO  (WO_NBRP + SN_NA*SN_MAXN*4)
#define WO_PAIRR (WO_NBRO + SN_NA*SN_MAXN*4)
#define WO_WPAIR (WO_PAIRR + SN_MAXP*4)
#define WO_X     (WO_WPAIR + SN_MAXP*SN_F*4)
#define WO_XF    (WO_X  + SN_NA*SN_F*4)
#define WO_XF2   (WO_XF + SN_NA*SN_F*4)
#define WO_EPART (WO_XF2 + SN_NA*SN_F*4)
#define SN_WSNEED (WO_EPART + SN_NA*4)

// dtype-generic scalar load: BF=0 -> f32, BF=1 -> bf16 (bit shift, no hip_bf16.h)
template <int BF>
__device__ __forceinline__ float ldx(const void* p, int idx) {
    if (BF) {
        unsigned int x = ((unsigned int)(((const unsigned short*)p)[idx])) << 16;
        float f; __builtin_memcpy(&f, &x, 4); return f;
    }
    return ((const float*)p)[idx];
}

__device__ __forceinline__ float sspf(float v) {
    float sp = fmaxf(v, 0.0f) + log1pf(__expf(-fabsf(v)));
    return sp - 0.69314718055994530942f;
}

// ---------------- dtype detect + counter zeroing ----------------
__global__ void k_detect(const void* box, int* flag, int* pcnt, int* ncnt) {
    int tid = threadIdx.x;
    for (int t = tid; t < SN_NA; t += 256) ncnt[t] = 0;
    if (tid == 0) {
        *pcnt = 0;
        float b0 = ((const float*)box)[0];   // f32: ~2.3 ; bf16-packed: denormal ~1e-41
        int isbf = !(b0 > 1e-3f && b0 < 1e3f);
        *flag = isbf;
    }
}

// ---------------- pair / neighbor-list build ----------------
template <int BF>
__device__ void build_body(const void* pos, const void* box,
                           int* pcnt, int* ncnt, int* nbrp, int* nbro, float* pairr) {
    int i = blockIdx.x;
    float c00 = ldx<BF>(box,0)*10.f, c01 = ldx<BF>(box,1)*10.f, c02 = ldx<BF>(box,2)*10.f;
    float c10 = ldx<BF>(box,3)*10.f, c11 = ldx<BF>(box,4)*10.f, c12 = ldx<BF>(box,5)*10.f;
    float c20 = ldx<BF>(box,6)*10.f, c21 = ldx<BF>(box,7)*10.f, c22 = ldx<BF>(box,8)*10.f;
    float det = c00*(c11*c22 - c12*c21) - c01*(c10*c22 - c12*c20) + c02*(c10*c21 - c11*c20);
    float id  = 1.0f / det;
    float i00 = (c11*c22 - c12*c21)*id, i01 = (c02*c21 - c01*c22)*id, i02 = (c01*c12 - c02*c11)*id;
    float i10 = (c12*c20 - c10*c22)*id, i11 = (c00*c22 - c02*c20)*id, i12 = (c02*c10 - c00*c12)*id;
    float i20 = (c10*c21 - c11*c20)*id, i21 = (c01*c20 - c00*c21)*id, i22 = (c00*c11 - c01*c10)*id;

    float xi = ldx<BF>(pos, i*3+0)*10.f;
    float yi = ldx<BF>(pos, i*3+1)*10.f;
    float zi = ldx<BF>(pos, i*3+2)*10.f;

    for (int j = threadIdx.x; j < SN_NA; j += 256) {
        if (j <= i) continue;
        float dx = xi - ldx<BF>(pos, j*3+0)*10.f;
        float dy = yi - ldx<BF>(pos, j*3+1)*10.f;
        float dz = zi - ldx<BF>(pos, j*3+2)*10.f;
        float fx = dx*i00 + dy*i10 + dz*i20;
        float fy = dx*i01 + dy*i11 + dz*i21;
        float fz = dx*i02 + dy*i12 + dz*i22;
        fx -= rintf(fx); fy -= rintf(fy); fz -= rintf(fz);
        float ax = fx*c00 + fy*c10 + fz*c20;
        float ay = fx*c01 + fy*c11 + fz*c21;
        float az = fx*c02 + fy*c12 + fz*c22;
        float r2 = ax*ax + ay*ay + az*az;
        if (r2 < SN_CUT2) {
            int p = atomicAdd(pcnt, 1);
            if (p < SN_MAXP) {
                pairr[p] = sqrtf(r2);
                int ki = atomicAdd(&ncnt[i], 1);
                if (ki < SN_MAXN) { nbrp[i*SN_MAXN+ki] = p; nbro[i*SN_MAXN+ki] = j; }
                int kj = atomicAdd(&ncnt[j], 1);
                if (kj < SN_MAXN) { nbrp[j*SN_MAXN+kj] = p; nbro[j*SN_MAXN+kj] = i; }
            }
        }
    }
}
__global__ void k_build(const int* flag, const void* pos, const void* box,
                        int* pcnt, int* ncnt, int* nbrp, int* nbro, float* pairr) {
    if (*flag) build_body<1>(pos, box, pcnt, ncnt, nbrp, nbro, pairr);
    else       build_body<0>(pos, box, pcnt, ncnt, nbrp, nbro, pairr);
}

// ---------------- x = embedding[Z]; xf = x @ Win[0] ----------------
template <int BF>
__device__ void init_body(const int* zn, const void* emb, const void* Win,
                          float* x, float* xf, float* xs) {
    int i = blockIdx.x;
    int f = threadIdx.x;
    float v = ldx<BF>(emb, zn[i]*SN_F + f);
    x[i*SN_F + f] = v;
    xs[f] = v;
    __syncthreads();
    float acc = 0.f;
    for (int k = 0; k < SN_F; k++)
        acc = fmaf(xs[k], ldx<BF>(Win, k*SN_F + f), acc);
    xf[i*SN_F + f] = acc;
}
__global__ void k_init(const int* flag, const int* zn, const void* emb, const void* Win,
                       float* x, float* xf) {
    __shared__ float xs[SN_F];
    if (*flag) init_body<1>(zn, emb, Win, x, xf, xs);
    else       init_body<0>(zn, emb, Win, x, xf, xs);
}

// ---------------- per-pair filter: W = (ssp(g@Wf1+bf1))@Wf2 + bf2 ----------------
template <int BF>
__device__ void filter_body(const float* pairr, const int* pcnt,
                            const void* Wf1, const void* bf1,
                            const void* Wf2, const void* bf2,
                            float* wpair, int lay, float* gs, float* hs) {
    int cnt = *pcnt; if (cnt > SN_MAXP) cnt = SN_MAXP;
    int p0 = blockIdx.x * SN_BP;
    if (p0 >= cnt) return;
    int tid = threadIdx.x;

    const float width = 5.0f / 49.0f;
    const float gamma = 0.5f / (width * width);
    for (int t = tid; t < SN_BP*52; t += 128) {
        int bp = t / 52, k = t % 52;
        float g = 0.0f;
        int p = p0 + bp;
        if (k < SN_G && p < cnt) {
            float d = pairr[p] - width * (float)k;
            g = __expf(-gamma * d * d);
        }
        gs[bp*52 + k] = g;
    }
    __syncthreads();

    int f = tid;
    int w1base = lay*SN_G*SN_F;
    float acc[SN_BP];
#pragma unroll
    for (int b = 0; b < SN_BP; b++) acc[b] = 0.f;
    for (int k = 0; k < SN_G; k++) {
        float w = ldx<BF>(Wf1, w1base + k*SN_F + f);
#pragma unroll
        for (int b = 0; b < SN_BP; b++)
            acc[b] = fmaf(gs[b*52 + k], w, acc[b]);
    }
    float bb1 = ldx<BF>(bf1, lay*SN_F + f);
#pragma unroll
    for (int b = 0; b < SN_BP; b++) hs[b*SN_F + f] = sspf(acc[b] + bb1);
    __syncthreads();

    int w2base = lay*SN_F*SN_F;
#pragma unroll
    for (int b = 0; b < SN_BP; b++) acc[b] = 0.f;
    for (int k = 0; k < SN_F; k++) {
        float w = ldx<BF>(Wf2, w2base + k*SN_F + f);
#pragma unroll
        for (int b = 0; b < SN_BP; b++)
            acc[b] = fmaf(hs[b*SN_F + k], w, acc[b]);
    }
    float bb2 = ldx<BF>(bf2, lay*SN_F + f);
#pragma unroll
    for (int b = 0; b < SN_BP; b++) {
        int p = p0 + b;
        if (p < cnt) wpair[p*SN_F + f] = acc[b] + bb2;
    }
}
__global__ void k_filter(const int* flag, const float* pairr, const int* pcnt,
                         const void* Wf1, const void* bf1, const void* Wf2, const void* bf2,
                         float* wpair, int lay) {
    __shared__ float gs[SN_BP*52];
    __shared__ float hs[SN_BP*SN_F];
    if (*flag) filter_body<1>(pairr, pcnt, Wf1, bf1, Wf2, bf2, wpair, lay, gs, hs);
    else       filter_body<0>(pairr, pcnt, Wf1, bf1, Wf2, bf2, wpair, lay, gs, hs);
}

// ---------------- aggregation + atom update (+ next-layer in2f) ----------------
template <int BF>
__device__ void update_body(const float* wpair, const int* ncnt,
                            const int* nbrp, const int* nbro,
                            const float* xf_in, float* x,
                            const void* W2, const void* b2,
                            const void* W3, const void* b3,
                            const void* Win, int lay, int layNext, float* xf_out,
                            float* ms, float* ts) {
    int a0 = blockIdx.x * 4;
    int f = threadIdx.x;
    int wbase2 = lay*SN_F*SN_F, bbase = lay*SN_F;

#pragma unroll
    for (int a = 0; a < 4; a++) {
        int i = a0 + a;
        int cn = ncnt[i]; if (cn > SN_MAXN) cn = SN_MAXN;
        float acc = 0.f;
        for (int k = 0; k < cn; k++) {
            int p = nbrp[i*SN_MAXN + k];
            int j = nbro[i*SN_MAXN + k];
            acc = fmaf(wpair[p*SN_F + f], xf_in[j*SN_F + f], acc);
        }
        ms[a*SN_F + f] = acc;
    }
    __syncthreads();

    float acc[4] = {0.f, 0.f, 0.f, 0.f};
    for (int k = 0; k < SN_F; k++) {
        float w = ldx<BF>(W2, wbase2 + k*SN_F + f);
#pragma unroll
        for (int a = 0; a < 4; a++)
            acc[a] = fmaf(ms[a*SN_F + k], w, acc[a]);
    }
    float bb2 = ldx<BF>(b2, bbase + f);
#pragma unroll
    for (int a = 0; a < 4; a++) ts[a*SN_F + f] = sspf(acc[a] + bb2);
    __syncthreads();

#pragma unroll
    for (int a = 0; a < 4; a++) acc[a] = 0.f;
    for (int k = 0; k < SN_F; k++) {
        float w = ldx<BF>(W3, wbase2 + k*SN_F + f);
#pragma unroll
        for (int a = 0; a < 4; a++)
            acc[a] = fmaf(ts[a*SN_F + k], w, acc[a]);
    }
    float bb3 = ldx<BF>(b3, bbase + f);
    float xnew[4];
#pragma unroll
    for (int a = 0; a < 4; a++) {
        xnew[a] = x[(a0+a)*SN_F + f] + acc[a] + bb3;
        x[(a0+a)*SN_F + f] = xnew[a];
    }

    if (layNext >= 0) {
        __syncthreads();
#pragma unroll
        for (int a = 0; a < 4; a++) ms[a*SN_F + f] = xnew[a];
        __syncthreads();
        int wbaseN = layNext*SN_F*SN_F;
#pragma unroll
        for (int a = 0; a < 4; a++) acc[a] = 0.f;
        for (int k = 0; k < SN_F; k++) {
            float w = ldx<BF>(Win, wbaseN + k*SN_F + f);
#pragma unroll
            for (int a = 0; a < 4; a++)
                acc[a] = fmaf(ms[a*SN_F + k], w, acc[a]);
        }
#pragma unroll
        for (int a = 0; a < 4; a++) xf_out[(a0+a)*SN_F + f] = acc[a];
    }
}
__global__ void k_update(const int* flag, const float* wpair, const int* ncnt,
                         const int* nbrp, const int* nbro,
                         const float* xf_in, float* x,
                         const void* W2, const void* b2, const void* W3, const void* b3,
                         const void* Win, int lay, int layNext, float* xf_out) {
    __shared__ float ms[4*SN_F];
    __shared__ float ts[4*SN_F];
    if (*flag) update_body<1>(wpair, ncnt, nbrp, nbro, xf_in, x, W2, b2, W3, b3, Win, lay, layNext, xf_out, ms, ts);
    else       update_body<0>(wpair, ncnt, nbrp, nbro, xf_in, x, W2, b2, W3, b3, Win, lay, layNext, xf_out, ms, ts);
}

// ---------------- energy head ----------------
template <int BF>
__device__ void head_body(const float* x, const void* Wo1, const void* bo1,
                          const void* Wo2, const void* bo2, float* epart, float* xs) {
    int a0 = blockIdx.x * 2;
    int tid = threadIdx.x;
    int a = tid >> 6, fo = tid & 63;
    xs[tid]       = x[a0*SN_F + tid];
    xs[SN_F+tid]  = x[(a0+1)*SN_F + tid];
    __syncthreads();
    float acc = 0.f;
    for (int k = 0; k < SN_F; k++)
        acc = fmaf(xs[a*SN_F + k], ldx<BF>(Wo1, k*64 + fo), acc);
    float h = sspf(acc + ldx<BF>(bo1, fo));
    float e = h * ldx<BF>(Wo2, fo);
#pragma unroll
    for (int off = 32; off > 0; off >>= 1) e += __shfl_down(e, off, 64);
    if (fo == 0) epart[a0 + a] = e + ldx<BF>(bo2, 0);
}
__global__ void k_head(const int* flag, const float* x,
                       const void* Wo1, const void* bo1, const void* Wo2, const void* bo2,
                       float* epart) {
    __shared__ float xs[2*SN_F];
    if (*flag) head_body<1>(x, Wo1, bo1, Wo2, bo2, epart, xs);
    else       head_body<0>(x, Wo1, bo1, Wo2, bo2, epart, xs);
}

// ---------------- final reduce + dtype-matched store ----------------
__global__ void k_reduce(const int* flag, const float* epart, void* out) {
    __shared__ float red[256];
    int tid = threadIdx.x;
    float s = 0.f;
    for (int idx = tid; idx < SN_NA; idx += 256) s += epart[idx];
    red[tid] = s;
    __syncthreads();
    for (int w = 128; w > 0; w >>= 1) {
        if (tid < w) red[tid] += red[tid + w];
        __syncthreads();
    }
    if (tid == 0) {
        float v = red[0];
        if (*flag) {
            unsigned int xbits; __builtin_memcpy(&xbits, &v, 4);
            unsigned short r = (unsigned short)((xbits + 0x7FFFu + ((xbits >> 16) & 1u)) >> 16);
            ((unsigned short*)out)[0] = r;
        } else {
            ((float*)out)[0] = v;
        }
    }
}

// sentinel: ws too small -> write bf16 1234.0 so the failure mode is identifiable
__global__ void k_fail(void* out) {
    ((unsigned short*)out)[0] = 0x449A;
}

extern "C" void kernel_launch(void* const* d_in, const int* in_sizes, int n_in,
                              void* d_out, int out_size, void* d_ws, size_t ws_size,
                              hipStream_t stream)
{
    const void* pos = d_in[0];
    const void* box = d_in[1];
    const int*  zn  = (const int*)d_in[2];
    const void* emb = d_in[3];
    const void* Wf1 = d_in[4];
    const void* bf1 = d_in[5];
    const void* Wf2 = d_in[6];
    const void* bf2 = d_in[7];
    const void* Win = d_in[8];
    const void* W2  = d_in[9];
    const void* b2  = d_in[10];
    const void* W3  = d_in[11];
    const void* b3  = d_in[12];
    const void* Wo1 = d_in[13];
    const void* bo1 = d_in[14];
    const void* Wo2 = d_in[15];
    const void* bo2 = d_in[16];

    if (ws_size < (size_t)SN_WSNEED) {
        k_fail<<<1, 1, 0, stream>>>(d_out);
        return;
    }

    char* ws = (char*)d_ws;
    int*   flag  = (int*)  (ws + WO_FLAG);
    int*   pcnt  = (int*)  (ws + WO_PCNT);
    int*   ncnt  = (int*)  (ws + WO_NCNT);
    int*   nbrp  = (int*)  (ws + WO_NBRP);
    int*   nbro  = (int*)  (ws + WO_NBRO);
    float* pairr = (float*)(ws + WO_PAIRR);
    float* wpair = (float*)(ws + WO_WPAIR);
    float* x     = (float*)(ws + WO_X);
    float* xfA   = (float*)(ws + WO_XF);
    float* xfB   = (float*)(ws + WO_XF2);
    float* epart = (float*)(ws + WO_EPART);

    k_detect<<<1, 256, 0, stream>>>(box, flag, pcnt, ncnt);
    k_build<<<SN_NA, 256, 0, stream>>>(flag, pos, box, pcnt, ncnt, nbrp, nbro, pairr);
    k_init<<<SN_NA, 128, 0, stream>>>(flag, zn, emb, Win, x, xfA);

    float* xf_in = xfA;
    float* xf_out = xfB;
    for (int l = 0; l < 3; l++) {
        k_filter<<<SN_MAXP/SN_BP, 128, 0, stream>>>(flag, pairr, pcnt,
            Wf1, bf1, Wf2, bf2, wpair, l);
        int layNext = (l < 2) ? (l + 1) : -1;
        k_update<<<SN_NA/4, 128, 0, stream>>>(flag, wpair, ncnt, nbrp, nbro,
            xf_in, x, W2, b2, W3, b3, Win, l, layNext, xf_out);
        float* t = xf_in; xf_in = xf_out; xf_out = t;
    }

    k_head<<<SN_NA/2, 128, 0, stream>>>(flag, x, Wo1, bo1, Wo2, bo2, epart);
    k_reduce<<<1, 256, 0, stream>>>(flag, epart, d_out);
}